// Round 4
// baseline (158.414 us; speedup 1.0000x reference)
//
#include <hip/hip_runtime.h>
#include <math.h>

#define BB 4
#define CC 256
#define NHEAD 4
#define DH 32
#define NN 4096
#define HID 128

typedef _Float16 f16;
typedef _Float16 f16x8 __attribute__((ext_vector_type(8)));
typedef _Float16 f16x4 __attribute__((ext_vector_type(4)));
typedef _Float16 f16x2 __attribute__((ext_vector_type(2)));
typedef float f32x4 __attribute__((ext_vector_type(4)));
typedef unsigned int u32x4 __attribute__((ext_vector_type(4)));

#define QPRESCALE 14.42695041f
#define NSHIFT 14.42695041f

#if __has_builtin(__builtin_amdgcn_exp2f)
#define EXP2F(x) __builtin_amdgcn_exp2f(x)
#else
#define EXP2F(x) __expf((x)*0.6931471805599453f)
#endif

__device__ __forceinline__ f16x8 cvt8(const float* p) {
    float4 a = *(const float4*)p;
    float4 b = *(const float4*)(p + 4);
    f16x8 r;
    r[0] = (f16)a.x; r[1] = (f16)a.y; r[2] = (f16)a.z; r[3] = (f16)a.w;
    r[4] = (f16)b.x; r[5] = (f16)b.y; r[6] = (f16)b.z; r[7] = (f16)b.w;
    return r;
}

// ---------------- kernel 0: prep — x transpose->f16, w/wo cvt ----------------
// x [b][c][i] f32 -> xT16 [b][i][c] f16 via 32c x 256i LDS tiles; RNE casts
// (identical rounding to the old in-loop (f16) conversions). Blocks 512..514
// convert w_qkv -> w16; block 515 converts w_out -> wo16.
__global__ __launch_bounds__(256) void prep(const float* __restrict__ x,
                                            const float* __restrict__ wq,
                                            const float* __restrict__ wo,
                                            f16* __restrict__ xt,
                                            f16* __restrict__ w16,
                                            f16* __restrict__ wo16) {
    int tb = blockIdx.x;
    if (tb < 512) {
        __shared__ f16 tile[256][36];   // [i][c_local], 72 B rows
        int b = tb >> 7, rem = tb & 127;
        int c0 = (rem >> 4) << 5;       // 8 c-tiles of 32
        int i0 = (rem & 15) << 8;       // 16 i-tiles of 256
        const float* xb = x + ((size_t)b * CC + c0) * NN + i0;
        int rp = threadIdx.x >> 4;      // 0..15: c row-pair
        int seg = threadIdx.x & 15;     // i segment
#pragma unroll
        for (int pass = 0; pass < 4; pass++) {
            int i = pass * 64 + seg * 4;
            float4 a = *(const float4*)(xb + (size_t)(2 * rp) * NN + i);
            float4 bq = *(const float4*)(xb + (size_t)(2 * rp + 1) * NN + i);
#pragma unroll
            for (int j = 0; j < 4; j++) {
                f16x2 pr;
                float aj = (j == 0) ? a.x : (j == 1) ? a.y : (j == 2) ? a.z : a.w;
                float bj = (j == 0) ? bq.x : (j == 1) ? bq.y : (j == 2) ? bq.z : bq.w;
                pr[0] = (f16)aj;
                pr[1] = (f16)bj;
                *(f16x2*)(&tile[i + j][2 * rp]) = pr;
            }
        }
        __syncthreads();
        f16* dst = xt + ((size_t)b * NN + i0) * CC + c0;
        int cq = threadIdx.x & 7;
        int ii = threadIdx.x >> 3;      // 32 i rows per pass
#pragma unroll
        for (int pass = 0; pass < 8; pass++) {
            int i = pass * 32 + ii;
            *(f16x4*)(dst + (size_t)i * CC + cq * 4) = *(const f16x4*)(&tile[i][cq * 4]);
        }
    } else {
        int k = tb - 512;               // 0..2: wq chunks, 3: wo
        const float* src = (k < 3) ? (wq + (size_t)k * 32768) : wo;
        f16* dst = (k < 3) ? (w16 + (size_t)k * 32768) : wo16;
        for (int e = threadIdx.x; e < 8192; e += 256) {
            float4 a = ((const float4*)src)[e];
            f16x4 s;
            s[0] = (f16)a.x; s[1] = (f16)a.y; s[2] = (f16)a.z; s[3] = (f16)a.w;
            ((f16x4*)dst)[e] = s;
        }
    }
}

// ---------------- kernel 1: qkv GEMM (all-f16 b128 loads) + l2norm ----------
// R3 analysis: old qkv_fused built B-frags from 8 scalar f32 loads + cvts per
// frag (128 scalar loads/wave/k-pass) — the scalar-bf16-load trap. With xT16
// and w16 both [row][k-contig] f16, every fragment is one b128 load.
__global__ __launch_bounds__(256) void qkv16(const f16* __restrict__ xt,
                                             const f16* __restrict__ w16,
                                             f16* __restrict__ qh,
                                             f16* __restrict__ kh,
                                             f16* __restrict__ vh) {
    int wave = threadIdx.x >> 6, lane = threadIdx.x & 63;
    int quad = lane >> 4, col = lane & 15;
    int b = blockIdx.z;
    int o0 = blockIdx.y * 64;
    int i0 = blockIdx.x * 128 + wave * 32;
    const f16* xb = xt + (size_t)b * NN * CC;

    f32x4 c[4][2];
#pragma unroll
    for (int mt = 0; mt < 4; mt++)
#pragma unroll
        for (int nt = 0; nt < 2; nt++) c[mt][nt] = f32x4{0.f, 0.f, 0.f, 0.f};

#pragma unroll
    for (int k0 = 0; k0 < CC; k0 += 32) {
        f16x8 a[4];
#pragma unroll
        for (int mt = 0; mt < 4; mt++)
            a[mt] = *(const f16x8*)(w16 + (size_t)(o0 + mt * 16 + col) * CC + k0 + quad * 8);
#pragma unroll
        for (int nt = 0; nt < 2; nt++) {
            f16x8 bf = *(const f16x8*)(xb + (size_t)(i0 + nt * 16 + col) * CC + k0 + quad * 8);
#pragma unroll
            for (int mt = 0; mt < 4; mt++)
                c[mt][nt] = __builtin_amdgcn_mfma_f32_16x16x32_f16(a[mt], bf, c[mt][nt], 0, 0, 0);
        }
    }

    if (o0 < 256) {
        int isQ = (o0 < 128);
        int obase = isQ ? o0 : (o0 - 128);
        f16* dst = isQ ? qh : kh;
        float pre = isQ ? QPRESCALE : 1.0f;
#pragma unroll
        for (int nt = 0; nt < 2; nt++) {
#pragma unroll
            for (int hh = 0; hh < 2; hh++) {
                float ss = 0.f;
#pragma unroll
                for (int m2 = 0; m2 < 2; m2++)
#pragma unroll
                    for (int r = 0; r < 4; r++) {
                        float v = c[hh * 2 + m2][nt][r];
                        ss = fmaf(v, v, ss);
                    }
                ss += __shfl_xor(ss, 16);
                ss += __shfl_xor(ss, 32);
                float inv = pre / fmaxf(sqrtf(ss), 1e-12f);
                int h = (obase + hh * 32) >> 5;
                size_t row = ((size_t)(b * 4 + h) * NN + i0 + nt * 16 + col) * 32;
#pragma unroll
                for (int m2 = 0; m2 < 2; m2++) {
                    f16x4 st;
#pragma unroll
                    for (int r = 0; r < 4; r++) st[r] = (f16)(c[hh * 2 + m2][nt][r] * inv);
                    *(f16x4*)(dst + row + m2 * 16 + quad * 4) = st;
                }
            }
        }
    } else {
        int o2 = o0 - 256;
#pragma unroll
        for (int nt = 0; nt < 2; nt++) {
            int i = i0 + nt * 16 + col;
#pragma unroll
            for (int mt = 0; mt < 4; mt++) {
                int h = (o2 + mt * 16) >> 5;
                int d = (mt & 1) * 16 + quad * 4;
#pragma unroll
                for (int r = 0; r < 4; r++)
                    vh[((size_t)(b * 4 + h) * 32 + d + r) * NN + i] = (f16)c[mt][nt][r];
            }
        }
    }
}

// ---------------- kernel 1-fallback: original fused qkv (small ws) ----------
__global__ __launch_bounds__(256) void qkv_fused(const float* __restrict__ x,
                                                 const float* __restrict__ wq,
                                                 f16* __restrict__ qh,
                                                 f16* __restrict__ kh,
                                                 f16* __restrict__ vh) {
    int wave = threadIdx.x >> 6, lane = threadIdx.x & 63;
    int quad = lane >> 4, col = lane & 15;
    int b = blockIdx.z;
    int o0 = blockIdx.y * 64;
    int i0 = blockIdx.x * 128 + wave * 32;
    const float* xb = x + (size_t)b * CC * NN;

    f32x4 c[4][2];
#pragma unroll
    for (int mt = 0; mt < 4; mt++)
#pragma unroll
        for (int nt = 0; nt < 2; nt++) c[mt][nt] = f32x4{0.f, 0.f, 0.f, 0.f};

#pragma unroll
    for (int k0 = 0; k0 < CC; k0 += 32) {
        f16x8 a[4];
#pragma unroll
        for (int mt = 0; mt < 4; mt++)
            a[mt] = cvt8(wq + (size_t)(o0 + mt * 16 + col) * CC + k0 + quad * 8);
#pragma unroll
        for (int nt = 0; nt < 2; nt++) {
            const float* xc = xb + (size_t)(k0 + quad * 8) * NN + i0 + nt * 16 + col;
            f16x8 bf;
#pragma unroll
            for (int j = 0; j < 8; j++) bf[j] = (f16)xc[(size_t)j * NN];
#pragma unroll
            for (int mt = 0; mt < 4; mt++)
                c[mt][nt] = __builtin_amdgcn_mfma_f32_16x16x32_f16(a[mt], bf, c[mt][nt], 0, 0, 0);
        }
    }

    if (o0 < 256) {
        int isQ = (o0 < 128);
        int obase = isQ ? o0 : (o0 - 128);
        f16* dst = isQ ? qh : kh;
        float pre = isQ ? QPRESCALE : 1.0f;
#pragma unroll
        for (int nt = 0; nt < 2; nt++) {
#pragma unroll
            for (int hh = 0; hh < 2; hh++) {
                float ss = 0.f;
#pragma unroll
                for (int m2 = 0; m2 < 2; m2++)
#pragma unroll
                    for (int r = 0; r < 4; r++) {
                        float v = c[hh * 2 + m2][nt][r];
                        ss = fmaf(v, v, ss);
                    }
                ss += __shfl_xor(ss, 16);
                ss += __shfl_xor(ss, 32);
                float inv = pre / fmaxf(sqrtf(ss), 1e-12f);
                int h = (obase + hh * 32) >> 5;
                size_t row = ((size_t)(b * 4 + h) * NN + i0 + nt * 16 + col) * 32;
#pragma unroll
                for (int m2 = 0; m2 < 2; m2++) {
                    f16x4 st;
#pragma unroll
                    for (int r = 0; r < 4; r++) st[r] = (f16)(c[hh * 2 + m2][nt][r] * inv);
                    *(f16x4*)(dst + row + m2 * 16 + quad * 4) = st;
                }
            }
        }
    } else {
        int o2 = o0 - 256;
#pragma unroll
        for (int nt = 0; nt < 2; nt++) {
            int i = i0 + nt * 16 + col;
#pragma unroll
            for (int mt = 0; mt < 4; mt++) {
                int h = (o2 + mt * 16) >> 5;
                int d = (mt & 1) * 16 + quad * 4;
#pragma unroll
                for (int r = 0; r < 4; r++)
                    vh[((size_t)(b * 4 + h) * 32 + d + r) * NN + i] = (f16)c[mt][nt][r];
            }
        }
    }
}

// ---------------- kernel 2: LDS-staged MFMA flash attention, key-split ------
#define KROW 40   // 32 d + 8 pad (f16) -> 80 B rows, b128-clean
#define VROW 72   // 64 keys + 8 pad   -> 144 B rows, b128-clean

__device__ __forceinline__ f16x8 expblk2(f32x4 sa, f32x4 sb) {
    u32x4 w;
    w[0] = __builtin_bit_cast(unsigned int,
            __builtin_amdgcn_cvt_pkrtz(EXP2F(sa[0]), EXP2F(sa[1])));
    w[1] = __builtin_bit_cast(unsigned int,
            __builtin_amdgcn_cvt_pkrtz(EXP2F(sa[2]), EXP2F(sa[3])));
    w[2] = __builtin_bit_cast(unsigned int,
            __builtin_amdgcn_cvt_pkrtz(EXP2F(sb[0]), EXP2F(sb[1])));
    w[3] = __builtin_bit_cast(unsigned int,
            __builtin_amdgcn_cvt_pkrtz(EXP2F(sb[2]), EXP2F(sb[3])));
    return __builtin_bit_cast(f16x8, w);
}

// one 32-key group (jb = 0 or 32) x 64 q (4 q-frags)
__device__ __forceinline__ void compute_g(const f16* kl, const f16* vl, int jb,
                                          int col, int quad, const f16x8 (&qB)[4],
                                          f32x4 (&o)[4][2], f32x4 (&lf)[4]) {
    f16x8 kA = *(const f16x8*)(kl + (jb + col) * KROW + quad * 8);
    f16x8 kB = *(const f16x8*)(kl + (jb + 16 + col) * KROW + quad * 8);
    f16x8 v0 = *(const f16x8*)(vl + col * VROW + jb + quad * 8);
    f16x8 v1 = *(const f16x8*)(vl + (16 + col) * VROW + jb + quad * 8);
    const f32x4 zs = {-NSHIFT, -NSHIFT, -NSHIFT, -NSHIFT};
    f16 one = (f16)1.0f;
    f16x8 ones = {one, one, one, one, one, one, one, one};
#pragma unroll
    for (int f = 0; f < 4; f++) {
        f32x4 sa = __builtin_amdgcn_mfma_f32_16x16x32_f16(kA, qB[f], zs, 0, 0, 0);
        f32x4 sb = __builtin_amdgcn_mfma_f32_16x16x32_f16(kB, qB[f], zs, 0, 0, 0);
        f16x8 p = expblk2(sa, sb);
        o[f][0] = __builtin_amdgcn_mfma_f32_16x16x32_f16(p, v0, o[f][0], 0, 0, 0);
        o[f][1] = __builtin_amdgcn_mfma_f32_16x16x32_f16(p, v1, o[f][1], 0, 0, 0);
        lf[f]   = __builtin_amdgcn_mfma_f32_16x16x32_f16(p, ones, lf[f], 0, 0, 0);
    }
}

template <int SPLIT>
__global__ __launch_bounds__(256, 4) void attn_mfma(const f16* __restrict__ qh,
                                                    const f16* __restrict__ kh,
                                                    const f16* __restrict__ vh,
                                                    float* __restrict__ op,
                                                    float* __restrict__ lp,
                                                    f16* __restrict__ att16) {
    __shared__ __align__(16) f16 klds[2][64 * KROW];
    __shared__ __align__(16) f16 vlds[2][32 * VROW];
    int t = threadIdx.x;
    int wave = t >> 6, lane = t & 63;
    int quad = lane >> 4, col = lane & 15;

    // grid = 256*SPLIT blocks; xcd grouping keeps K/V L2-resident (2 bh/XCD).
    int bid = blockIdx.x;
    int xcd = bid & 7;
    int slot = bid >> 3;                      // 0 .. 32*SPLIT-1
    int bh = xcd * 2 + slot / (16 * SPLIT);   // 0..15
    int rem = slot % (16 * SPLIT);
    int s = rem >> 4;                         // 0..SPLIT-1
    int i0 = (rem & 15) * 256;
    int iw = i0 + wave * 64;

    const int NT = 64 / SPLIT;                // 64-key tiles per block
    int kbase = s * (NN / SPLIT);

    const f16* qb = qh + (size_t)bh * NN * 32;
    const f16* kb = kh + (size_t)bh * NN * 32 + (size_t)kbase * 32;
    const f16* vb = vh + (size_t)bh * 32 * NN + kbase;

    f16x8 qB[4];
#pragma unroll
    for (int f = 0; f < 4; f++)
        qB[f] = *(const f16x8*)(qb + (size_t)(iw + f * 16 + col) * 32 + quad * 8);

    f32x4 o[4][2], lf[4];
#pragma unroll
    for (int f = 0; f < 4; f++) {
        o[f][0] = f32x4{0.f, 0.f, 0.f, 0.f};
        o[f][1] = f32x4{0.f, 0.f, 0.f, 0.f};
        lf[f]   = f32x4{0.f, 0.f, 0.f, 0.f};
    }

    // staging: K rows gathered in PV-permuted order (ksrc bijection) so P
    // frag concat is the native 16x16x32 A layout; V natural [dh][key].
    int ktr = t >> 2, kts = t & 3;
    int ksrc = (ktr & 32) | ((ktr & 12) << 1) | ((ktr & 16) >> 2) | (ktr & 3);
    int vtr = t >> 3, vts = t & 7;

    f16x8 kr, vr;
    kr = *(const f16x8*)(kb + (size_t)(0 + ksrc) * 32 + kts * 8);
    vr = *(const f16x8*)(vb + (size_t)vtr * NN + 0 + vts * 8);
    *(f16x8*)(&klds[0][0] + ktr * KROW + kts * 8) = kr;
    *(f16x8*)(&vlds[0][0] + vtr * VROW + vts * 8) = vr;
    __syncthreads();
    kr = *(const f16x8*)(kb + (size_t)(64 + ksrc) * 32 + kts * 8);
    vr = *(const f16x8*)(vb + (size_t)vtr * NN + 64 + vts * 8);

    for (int tile = 0; tile < NT - 2; tile++) {
        int buf = tile & 1;
        const f16* kl = &klds[buf][0];
        const f16* vl = &vlds[buf][0];
        compute_g(kl, vl, 0, col, quad, qB, o, lf);
        compute_g(kl, vl, 32, col, quad, qB, o, lf);
        *(f16x8*)(&klds[buf ^ 1][0] + ktr * KROW + kts * 8) = kr;
        *(f16x8*)(&vlds[buf ^ 1][0] + vtr * VROW + vts * 8) = vr;
        __syncthreads();
        int j0 = (tile + 2) * 64;
        kr = *(const f16x8*)(kb + (size_t)(j0 + ksrc) * 32 + kts * 8);
        vr = *(const f16x8*)(vb + (size_t)vtr * NN + j0 + vts * 8);
    }
    {   // tile NT-2 (buf 0); kr/vr hold tile NT-1
        compute_g(&klds[0][0], &vlds[0][0], 0, col, quad, qB, o, lf);
        compute_g(&klds[0][0], &vlds[0][0], 32, col, quad, qB, o, lf);
        *(f16x8*)(&klds[1][0] + ktr * KROW + kts * 8) = kr;
        *(f16x8*)(&vlds[1][0] + vtr * VROW + vts * 8) = vr;
        __syncthreads();
    }
    {   // tile NT-1 (buf 1)
        compute_g(&klds[1][0], &vlds[1][0], 0, col, quad, qB, o, lf);
        compute_g(&klds[1][0], &vlds[1][0], 32, col, quad, qB, o, lf);
    }

    // lf[f][r] = sum_k p for query row iw + f*16 + quad*4 + r (replicated
    // across col lanes).
    if constexpr (SPLIT == 1) {
        int b = bh >> 2, h = bh & 3;
        f16* ab = att16 + (size_t)b * NN * HID + h * 32;
#pragma unroll
        for (int f = 0; f < 4; f++)
#pragma unroll
            for (int r = 0; r < 4; r++) {
                float inv = __builtin_amdgcn_rcpf(lf[f][r]);
                size_t row = (size_t)(iw + f * 16 + quad * 4 + r) * HID;
                ab[row + col]      = (f16)(o[f][0][r] * inv);
                ab[row + 16 + col] = (f16)(o[f][1][r] * inv);
            }
    } else {
        // f32 partials: op[(s*16+bh)][q][dh], lp[(s*16+bh)][q]
        float* ob = op + (size_t)(s * 16 + bh) * NN * 32;
#pragma unroll
        for (int f = 0; f < 4; f++)
#pragma unroll
            for (int r = 0; r < 4; r++) {
                size_t rr = (size_t)(iw + f * 16 + quad * 4 + r) * 32;
                ob[rr + col]      = o[f][0][r];
                ob[rr + 16 + col] = o[f][1][r];
            }
        if (col == 0) {
            float* lb = lp + (size_t)(s * 16 + bh) * NN;
#pragma unroll
            for (int f = 0; f < 4; f++)
#pragma unroll
                for (int r = 0; r < 4; r++)
                    lb[iw + f * 16 + quad * 4 + r] = lf[f][r];
        }
    }
}

// ---------------- kernel 2b: combine split partials -> att16 ----------------
__global__ __launch_bounds__(256) void attn_combine(const float* __restrict__ op,
                                                    const float* __restrict__ lp,
                                                    f16* __restrict__ att16,
                                                    int nsplit) {
    int gid = blockIdx.x * 256 + threadIdx.x;   // 16*4096 rows * 8 segs
    int rowid = gid >> 3;
    int seg = gid & 7;
    int bh = rowid >> 12;
    int q = rowid & 4095;

    float l = 0.f;
    f32x4 acc = {0.f, 0.f, 0.f, 0.f};
    for (int s = 0; s < nsplit; s++) {
        l += lp[(size_t)(s * 16 + bh) * NN + q];
        f32x4 a = *(const f32x4*)(op + ((size_t)(s * 16 + bh) * NN + q) * 32 + seg * 4);
        acc += a;
    }
    float inv = __builtin_amdgcn_rcpf(l);
    int b = bh >> 2, h = bh & 3;
    f16x4 st;
    st[0] = (f16)(acc[0] * inv);
    st[1] = (f16)(acc[1] * inv);
    st[2] = (f16)(acc[2] * inv);
    st[3] = (f16)(acc[3] * inv);
    *(f16x4*)(att16 + ((size_t)b * NN + q) * HID + h * 32 + seg * 4) = st;
}

// ---------------- kernel 3: output projection (MFMA) + bias ----------------
template <bool W16>
__global__ __launch_bounds__(256) void out_mfma(const f16* __restrict__ att16,
                                                const float* __restrict__ wo,
                                                const f16* __restrict__ wo16,
                                                const float* __restrict__ bo,
                                                float* __restrict__ out) {
    int wave = threadIdx.x >> 6, lane = threadIdx.x & 63;
    int quad = lane >> 4, col = lane & 15;
    int b = blockIdx.z;
    int i0 = (blockIdx.x * 4 + wave) * 32;
    int o0 = blockIdx.y * 64;
    const f16* ab = att16 + (size_t)b * NN * HID;

    const f32x4 z = {0.f, 0.f, 0.f, 0.f};
    f32x4 c[2][4];
#pragma unroll
    for (int it = 0; it < 2; it++)
#pragma unroll
        for (int ot = 0; ot < 4; ot++) c[it][ot] = z;

#pragma unroll
    for (int k0 = 0; k0 < HID; k0 += 32) {
        f16x8 a0 = *(const f16x8*)(ab + (size_t)(i0 + col) * HID + k0 + quad * 8);
        f16x8 a1 = *(const f16x8*)(ab + (size_t)(i0 + 16 + col) * HID + k0 + quad * 8);
#pragma unroll
        for (int ot = 0; ot < 4; ot++) {
            f16x8 bf;
            if constexpr (W16)
                bf = *(const f16x8*)(wo16 + (size_t)(o0 + ot * 16 + col) * HID + k0 + quad * 8);
            else
                bf = cvt8(wo + (size_t)(o0 + ot * 16 + col) * HID + k0 + quad * 8);
            c[0][ot] = __builtin_amdgcn_mfma_f32_16x16x32_f16(a0, bf, c[0][ot], 0, 0, 0);
            c[1][ot] = __builtin_amdgcn_mfma_f32_16x16x32_f16(a1, bf, c[1][ot], 0, 0, 0);
        }
    }

#pragma unroll
    for (int it = 0; it < 2; it++)
#pragma unroll
        for (int ot = 0; ot < 4; ot++) {
            int o = o0 + ot * 16 + col;
            float bias = bo[o];
            int i = i0 + it * 16 + quad * 4;
            float4 st = {c[it][ot][0] + bias, c[it][ot][1] + bias,
                         c[it][ot][2] + bias, c[it][ot][3] + bias};
            *(float4*)(out + ((size_t)b * CC + o) * NN + i) = st;
        }
}

extern "C" void kernel_launch(void* const* d_in, const int* in_sizes, int n_in,
                              void* d_out, int out_size, void* d_ws, size_t ws_size,
                              hipStream_t stream) {
    const float* x     = (const float*)d_in[0];
    const float* w_qkv = (const float*)d_in[1];
    const float* w_out = (const float*)d_in[2];
    const float* b_out = (const float*)d_in[3];
    float* out = (float*)d_out;

    char* ws = (char*)d_ws;
    f16* qh    = (f16*)(ws);                        // 4 MB
    f16* kh    = (f16*)(ws + (4u << 20));           // 4 MB
    f16* vh    = (f16*)(ws + (8u << 20));           // 4 MB
    f16* att16 = (f16*)(ws + (12u << 20));          // 4 MB
    // xt (8 MB @16) aliases op: xt is dead before attn writes op (stream order)
    f16* xt = (f16*)(ws + (16ull << 20));

    if (ws_size >= (50ull << 20)) {
        // SPLIT=4: op 32 MB @16, lp 1 MB @48, wo16 64 KB @49, w16 192 KB @49.0625
        float* op = (float*)(ws + (16ull << 20));
        float* lp = (float*)(ws + (48ull << 20));
        f16* wo16 = (f16*)(ws + (49ull << 20));
        f16* w16  = (f16*)(ws + (49ull << 20) + (64u << 10));
        prep<<<dim3(516), 256, 0, stream>>>(x, w_qkv, w_out, xt, w16, wo16);
        qkv16<<<dim3(NN / 128, 384 / 64, BB), 256, 0, stream>>>(xt, w16, qh, kh, vh);
        attn_mfma<4><<<dim3(1024), 256, 0, stream>>>(qh, kh, vh, op, lp, att16);
        attn_combine<<<dim3(2048), 256, 0, stream>>>(op, lp, att16, 4);
        out_mfma<true><<<dim3(NN / 128, CC / 64, BB), 256, 0, stream>>>(att16, w_out, wo16, b_out, out);
    } else if (ws_size >= (33ull << 20)) {
        // SPLIT=2: op 16 MB @16, lp 0.5 MB @32, wo16 @32.5, w16 @32.5625
        float* op = (float*)(ws + (16ull << 20));
        float* lp = (float*)(ws + (32ull << 20));
        f16* wo16 = (f16*)(ws + (32ull << 20) + (512u << 10));
        f16* w16  = (f16*)(ws + (32ull << 20) + (576u << 10));
        prep<<<dim3(516), 256, 0, stream>>>(x, w_qkv, w_out, xt, w16, wo16);
        qkv16<<<dim3(NN / 128, 384 / 64, BB), 256, 0, stream>>>(xt, w16, qh, kh, vh);
        attn_mfma<2><<<dim3(512), 256, 0, stream>>>(qh, kh, vh, op, lp, att16);
        attn_combine<<<dim3(2048), 256, 0, stream>>>(op, lp, att16, 2);
        out_mfma<true><<<dim3(NN / 128, CC / 64, BB), 256, 0, stream>>>(att16, w_out, wo16, b_out, out);
    } else {
        qkv_fused<<<dim3(NN / 128, 384 / 64, BB), 256, 0, stream>>>(x, w_qkv, qh, kh, vh);
        attn_mfma<1><<<dim3(256), 256, 0, stream>>>(qh, kh, vh, nullptr, nullptr, att16);
        out_mfma<false><<<dim3(NN / 128, CC / 64, BB), 256, 0, stream>>>(att16, w_out, nullptr, b_out, out);
    }
}

// Round 5
// 153.509 us; speedup vs baseline: 1.0320x; 1.0320x over previous
//
#include <hip/hip_runtime.h>
#include <math.h>

#define BB 4
#define CC 256
#define NHEAD 4
#define DH 32
#define NN 4096
#define HID 128

typedef _Float16 f16;
typedef _Float16 f16x8 __attribute__((ext_vector_type(8)));
typedef _Float16 f16x4 __attribute__((ext_vector_type(4)));
typedef float f32x4 __attribute__((ext_vector_type(4)));
typedef unsigned int u32x4 __attribute__((ext_vector_type(4)));

#define QPRESCALE 14.42695041f
#define NSHIFT 14.42695041f

#if __has_builtin(__builtin_amdgcn_exp2f)
#define EXP2F(x) __builtin_amdgcn_exp2f(x)
#else
#define EXP2F(x) __expf((x)*0.6931471805599453f)
#endif

__device__ __forceinline__ f16x8 cvt8(const float* p) {
    float4 a = *(const float4*)p;
    float4 b = *(const float4*)(p + 4);
    f16x8 r;
    r[0] = (f16)a.x; r[1] = (f16)a.y; r[2] = (f16)a.z; r[3] = (f16)a.w;
    r[4] = (f16)b.x; r[5] = (f16)b.y; r[6] = (f16)b.z; r[7] = (f16)b.w;
    return r;
}

// ---------------- kernel 1: qkv GEMM, in-LDS x transpose + l2norm ----------
// R4 lesson: prep's separate 96 MB transpose pass + 48 MB xt re-read cost more
// than qkv16 saved. Here the f32->f16 transpose happens inside the GEMM:
// block = 32 i x 384 o (all outputs -> x read ONCE), per k-step a 32i x 32c
// f32 slab is staged to a 2.5 KB LDS tile ([i][c], f16, <=2-way banks).
// Wave w owns o in [w*96, w*96+96): 6 m-frags; x gives 2 n-frags.
#define XROW 40   // 32 c + 8 pad

__global__ __launch_bounds__(256) void qkv_mega(const float* __restrict__ x,
                                                const float* __restrict__ wq,
                                                f16* __restrict__ qh,
                                                f16* __restrict__ kh,
                                                f16* __restrict__ vh) {
    __shared__ __align__(16) f16 xl[32 * XROW];
    int t = threadIdx.x;
    int wave = t >> 6, lane = t & 63;
    int quad = lane >> 4, col = lane & 15;
    int b = blockIdx.z;
    int i0 = blockIdx.x * 32;
    int o0w = wave * 96;

    int sc = t >> 3;      // 0..31: local c row
    int iseg = t & 7;     // i group of 4 (lanes 0..7 contiguous in i)
    const float* xb = x + (size_t)b * CC * NN + i0 + iseg * 4;

    f32x4 c[6][2];
#pragma unroll
    for (int mt = 0; mt < 6; mt++)
#pragma unroll
        for (int nt = 0; nt < 2; nt++) c[mt][nt] = f32x4{0.f, 0.f, 0.f, 0.f};

#pragma unroll
    for (int k0 = 0; k0 < CC; k0 += 32) {
        float4 xv = *(const float4*)(xb + (size_t)(k0 + sc) * NN);
        __syncthreads();   // prior iter's frag reads done before overwrite
        xl[(iseg * 4 + 0) * XROW + sc] = (f16)xv.x;
        xl[(iseg * 4 + 1) * XROW + sc] = (f16)xv.y;
        xl[(iseg * 4 + 2) * XROW + sc] = (f16)xv.z;
        xl[(iseg * 4 + 3) * XROW + sc] = (f16)xv.w;
        __syncthreads();
        f16x8 bf0 = *(const f16x8*)(xl + (size_t)col * XROW + quad * 8);
        f16x8 bf1 = *(const f16x8*)(xl + (size_t)(16 + col) * XROW + quad * 8);
#pragma unroll
        for (int mt = 0; mt < 6; mt++) {
            f16x8 a = cvt8(wq + (size_t)(o0w + mt * 16 + col) * CC + k0 + quad * 8);
            c[mt][0] = __builtin_amdgcn_mfma_f32_16x16x32_f16(a, bf0, c[mt][0], 0, 0, 0);
            c[mt][1] = __builtin_amdgcn_mfma_f32_16x16x32_f16(a, bf1, c[mt][1], 0, 0, 0);
        }
    }

#pragma unroll
    for (int hh = 0; hh < 3; hh++) {
        int oh = o0w + hh * 32;         // wave-uniform head base
        if (oh < 256) {                  // Q or K: l2norm over the 32 dh rows
            int isQ = (oh < 128);
            f16* dst = isQ ? qh : kh;
            int h = (isQ ? oh : (oh - 128)) >> 5;
            float pre = isQ ? QPRESCALE : 1.0f;
#pragma unroll
            for (int nt = 0; nt < 2; nt++) {
                float ss = 0.f;
#pragma unroll
                for (int m2 = 0; m2 < 2; m2++)
#pragma unroll
                    for (int r = 0; r < 4; r++) {
                        float v = c[hh * 2 + m2][nt][r];
                        ss = fmaf(v, v, ss);
                    }
                ss += __shfl_xor(ss, 16);
                ss += __shfl_xor(ss, 32);
                float inv = pre / fmaxf(sqrtf(ss), 1e-12f);
                size_t row = ((size_t)(b * 4 + h) * NN + i0 + nt * 16 + col) * 32;
#pragma unroll
                for (int m2 = 0; m2 < 2; m2++) {
                    f16x4 st;
#pragma unroll
                    for (int r = 0; r < 4; r++) st[r] = (f16)(c[hh * 2 + m2][nt][r] * inv);
                    *(f16x4*)(dst + row + m2 * 16 + quad * 4) = st;
                }
            }
        } else {                         // V: [bh][d][i] layout
            int h = (oh - 256) >> 5;
#pragma unroll
            for (int nt = 0; nt < 2; nt++) {
                int i = i0 + nt * 16 + col;
#pragma unroll
                for (int m2 = 0; m2 < 2; m2++)
#pragma unroll
                    for (int r = 0; r < 4; r++)
                        vh[((size_t)(b * 4 + h) * 32 + m2 * 16 + quad * 4 + r) * NN + i] =
                            (f16)c[hh * 2 + m2][nt][r];
            }
        }
    }
}

// ---------------- kernel 2: LDS-staged MFMA flash attention, key-split ------
#define KROW 40   // 32 d + 8 pad (f16) -> 80 B rows, b128-clean
#define VROW 72   // 64 keys + 8 pad   -> 144 B rows, b128-clean

__device__ __forceinline__ f16x8 expblk2(f32x4 sa, f32x4 sb) {
    u32x4 w;
    w[0] = __builtin_bit_cast(unsigned int,
            __builtin_amdgcn_cvt_pkrtz(EXP2F(sa[0]), EXP2F(sa[1])));
    w[1] = __builtin_bit_cast(unsigned int,
            __builtin_amdgcn_cvt_pkrtz(EXP2F(sa[2]), EXP2F(sa[3])));
    w[2] = __builtin_bit_cast(unsigned int,
            __builtin_amdgcn_cvt_pkrtz(EXP2F(sb[0]), EXP2F(sb[1])));
    w[3] = __builtin_bit_cast(unsigned int,
            __builtin_amdgcn_cvt_pkrtz(EXP2F(sb[2]), EXP2F(sb[3])));
    return __builtin_bit_cast(f16x8, w);
}

// one 32-key group (jb = 0 or 32) x 64 q (4 q-frags)
__device__ __forceinline__ void compute_g(const f16* kl, const f16* vl, int jb,
                                          int col, int quad, const f16x8 (&qB)[4],
                                          f32x4 (&o)[4][2], f32x4 (&lf)[4]) {
    f16x8 kA = *(const f16x8*)(kl + (jb + col) * KROW + quad * 8);
    f16x8 kB = *(const f16x8*)(kl + (jb + 16 + col) * KROW + quad * 8);
    f16x8 v0 = *(const f16x8*)(vl + col * VROW + jb + quad * 8);
    f16x8 v1 = *(const f16x8*)(vl + (16 + col) * VROW + jb + quad * 8);
    const f32x4 zs = {-NSHIFT, -NSHIFT, -NSHIFT, -NSHIFT};
    f16 one = (f16)1.0f;
    f16x8 ones = {one, one, one, one, one, one, one, one};
#pragma unroll
    for (int f = 0; f < 4; f++) {
        f32x4 sa = __builtin_amdgcn_mfma_f32_16x16x32_f16(kA, qB[f], zs, 0, 0, 0);
        f32x4 sb = __builtin_amdgcn_mfma_f32_16x16x32_f16(kB, qB[f], zs, 0, 0, 0);
        f16x8 p = expblk2(sa, sb);
        o[f][0] = __builtin_amdgcn_mfma_f32_16x16x32_f16(p, v0, o[f][0], 0, 0, 0);
        o[f][1] = __builtin_amdgcn_mfma_f32_16x16x32_f16(p, v1, o[f][1], 0, 0, 0);
        lf[f]   = __builtin_amdgcn_mfma_f32_16x16x32_f16(p, ones, lf[f], 0, 0, 0);
    }
}

template <int SPLIT>
__global__ __launch_bounds__(256, 4) void attn_mfma(const f16* __restrict__ qh,
                                                    const f16* __restrict__ kh,
                                                    const f16* __restrict__ vh,
                                                    float* __restrict__ op,
                                                    float* __restrict__ lp,
                                                    f16* __restrict__ att16) {
    __shared__ __align__(16) f16 klds[2][64 * KROW];
    __shared__ __align__(16) f16 vlds[2][32 * VROW];
    int t = threadIdx.x;
    int wave = t >> 6, lane = t & 63;
    int quad = lane >> 4, col = lane & 15;

    // grid = 256*SPLIT blocks; xcd grouping keeps K/V L2-resident (2 bh/XCD).
    int bid = blockIdx.x;
    int xcd = bid & 7;
    int slot = bid >> 3;                      // 0 .. 32*SPLIT-1
    int bh = xcd * 2 + slot / (16 * SPLIT);   // 0..15
    int rem = slot % (16 * SPLIT);
    int s = rem >> 4;                         // 0..SPLIT-1
    int i0 = (rem & 15) * 256;
    int iw = i0 + wave * 64;

    const int NT = 64 / SPLIT;                // 64-key tiles per block
    int kbase = s * (NN / SPLIT);

    const f16* qb = qh + (size_t)bh * NN * 32;
    const f16* kb = kh + (size_t)bh * NN * 32 + (size_t)kbase * 32;
    const f16* vb = vh + (size_t)bh * 32 * NN + kbase;

    f16x8 qB[4];
#pragma unroll
    for (int f = 0; f < 4; f++)
        qB[f] = *(const f16x8*)(qb + (size_t)(iw + f * 16 + col) * 32 + quad * 8);

    f32x4 o[4][2], lf[4];
#pragma unroll
    for (int f = 0; f < 4; f++) {
        o[f][0] = f32x4{0.f, 0.f, 0.f, 0.f};
        o[f][1] = f32x4{0.f, 0.f, 0.f, 0.f};
        lf[f]   = f32x4{0.f, 0.f, 0.f, 0.f};
    }

    // staging: K rows gathered in PV-permuted order (ksrc bijection) so P
    // frag concat is the native 16x16x32 A layout; V natural [dh][key].
    int ktr = t >> 2, kts = t & 3;
    int ksrc = (ktr & 32) | ((ktr & 12) << 1) | ((ktr & 16) >> 2) | (ktr & 3);
    int vtr = t >> 3, vts = t & 7;

    f16x8 kr, vr;
    kr = *(const f16x8*)(kb + (size_t)(0 + ksrc) * 32 + kts * 8);
    vr = *(const f16x8*)(vb + (size_t)vtr * NN + 0 + vts * 8);
    *(f16x8*)(&klds[0][0] + ktr * KROW + kts * 8) = kr;
    *(f16x8*)(&vlds[0][0] + vtr * VROW + vts * 8) = vr;
    __syncthreads();
    kr = *(const f16x8*)(kb + (size_t)(64 + ksrc) * 32 + kts * 8);
    vr = *(const f16x8*)(vb + (size_t)vtr * NN + 64 + vts * 8);

    for (int tile = 0; tile < NT - 2; tile++) {
        int buf = tile & 1;
        const f16* kl = &klds[buf][0];
        const f16* vl = &vlds[buf][0];
        compute_g(kl, vl, 0, col, quad, qB, o, lf);
        compute_g(kl, vl, 32, col, quad, qB, o, lf);
        *(f16x8*)(&klds[buf ^ 1][0] + ktr * KROW + kts * 8) = kr;
        *(f16x8*)(&vlds[buf ^ 1][0] + vtr * VROW + vts * 8) = vr;
        __syncthreads();
        int j0 = (tile + 2) * 64;
        kr = *(const f16x8*)(kb + (size_t)(j0 + ksrc) * 32 + kts * 8);
        vr = *(const f16x8*)(vb + (size_t)vtr * NN + j0 + vts * 8);
    }
    {   // tile NT-2 (buf 0); kr/vr hold tile NT-1
        compute_g(&klds[0][0], &vlds[0][0], 0, col, quad, qB, o, lf);
        compute_g(&klds[0][0], &vlds[0][0], 32, col, quad, qB, o, lf);
        *(f16x8*)(&klds[1][0] + ktr * KROW + kts * 8) = kr;
        *(f16x8*)(&vlds[1][0] + vtr * VROW + vts * 8) = vr;
        __syncthreads();
    }
    {   // tile NT-1 (buf 1)
        compute_g(&klds[1][0], &vlds[1][0], 0, col, quad, qB, o, lf);
        compute_g(&klds[1][0], &vlds[1][0], 32, col, quad, qB, o, lf);
    }

    // lf[f][r] = sum_k p for query row iw + f*16 + quad*4 + r (replicated
    // across col lanes).
    if constexpr (SPLIT == 1) {
        int b = bh >> 2, h = bh & 3;
        f16* ab = att16 + (size_t)b * NN * HID + h * 32;
#pragma unroll
        for (int f = 0; f < 4; f++)
#pragma unroll
            for (int r = 0; r < 4; r++) {
                float inv = __builtin_amdgcn_rcpf(lf[f][r]);
                size_t row = (size_t)(iw + f * 16 + quad * 4 + r) * HID;
                ab[row + col]      = (f16)(o[f][0][r] * inv);
                ab[row + 16 + col] = (f16)(o[f][1][r] * inv);
            }
    } else {
        // f32 partials: op[(s*16+bh)][q][dh], lp[(s*16+bh)][q]
        float* ob = op + (size_t)(s * 16 + bh) * NN * 32;
#pragma unroll
        for (int f = 0; f < 4; f++)
#pragma unroll
            for (int r = 0; r < 4; r++) {
                size_t rr = (size_t)(iw + f * 16 + quad * 4 + r) * 32;
                ob[rr + col]      = o[f][0][r];
                ob[rr + 16 + col] = o[f][1][r];
            }
        if (col == 0) {
            float* lb = lp + (size_t)(s * 16 + bh) * NN;
#pragma unroll
            for (int f = 0; f < 4; f++)
#pragma unroll
                for (int r = 0; r < 4; r++)
                    lb[iw + f * 16 + quad * 4 + r] = lf[f][r];
        }
    }
}

// ---------------- kernel 2b: combine split partials -> att16 ----------------
__global__ __launch_bounds__(256) void attn_combine(const float* __restrict__ op,
                                                    const float* __restrict__ lp,
                                                    f16* __restrict__ att16,
                                                    int nsplit) {
    int gid = blockIdx.x * 256 + threadIdx.x;   // 16*4096 rows * 8 segs
    int rowid = gid >> 3;
    int seg = gid & 7;
    int bh = rowid >> 12;
    int q = rowid & 4095;

    float l = 0.f;
    f32x4 acc = {0.f, 0.f, 0.f, 0.f};
    for (int s = 0; s < nsplit; s++) {
        l += lp[(size_t)(s * 16 + bh) * NN + q];
        f32x4 a = *(const f32x4*)(op + ((size_t)(s * 16 + bh) * NN + q) * 32 + seg * 4);
        acc += a;
    }
    float inv = __builtin_amdgcn_rcpf(l);
    int b = bh >> 2, h = bh & 3;
    f16x4 st;
    st[0] = (f16)(acc[0] * inv);
    st[1] = (f16)(acc[1] * inv);
    st[2] = (f16)(acc[2] * inv);
    st[3] = (f16)(acc[3] * inv);
    *(f16x4*)(att16 + ((size_t)b * NN + q) * HID + h * 32 + seg * 4) = st;
}

// ---------------- kernel 3: output projection (MFMA) + bias ----------------
__global__ __launch_bounds__(256) void out_mfma(const f16* __restrict__ att16,
                                                const float* __restrict__ wo,
                                                const float* __restrict__ bo,
                                                float* __restrict__ out) {
    int wave = threadIdx.x >> 6, lane = threadIdx.x & 63;
    int quad = lane >> 4, col = lane & 15;
    int b = blockIdx.z;
    int i0 = (blockIdx.x * 4 + wave) * 32;
    int o0 = blockIdx.y * 64;
    const f16* ab = att16 + (size_t)b * NN * HID;

    const f32x4 z = {0.f, 0.f, 0.f, 0.f};
    f32x4 c[2][4];
#pragma unroll
    for (int it = 0; it < 2; it++)
#pragma unroll
        for (int ot = 0; ot < 4; ot++) c[it][ot] = z;

#pragma unroll
    for (int k0 = 0; k0 < HID; k0 += 32) {
        f16x8 a0 = *(const f16x8*)(ab + (size_t)(i0 + col) * HID + k0 + quad * 8);
        f16x8 a1 = *(const f16x8*)(ab + (size_t)(i0 + 16 + col) * HID + k0 + quad * 8);
#pragma unroll
        for (int ot = 0; ot < 4; ot++) {
            f16x8 bf = cvt8(wo + (size_t)(o0 + ot * 16 + col) * HID + k0 + quad * 8);
            c[0][ot] = __builtin_amdgcn_mfma_f32_16x16x32_f16(a0, bf, c[0][ot], 0, 0, 0);
            c[1][ot] = __builtin_amdgcn_mfma_f32_16x16x32_f16(a1, bf, c[1][ot], 0, 0, 0);
        }
    }

#pragma unroll
    for (int it = 0; it < 2; it++)
#pragma unroll
        for (int ot = 0; ot < 4; ot++) {
            int o = o0 + ot * 16 + col;
            float bias = bo[o];
            int i = i0 + it * 16 + quad * 4;
            float4 st = {c[it][ot][0] + bias, c[it][ot][1] + bias,
                         c[it][ot][2] + bias, c[it][ot][3] + bias};
            *(float4*)(out + ((size_t)b * CC + o) * NN + i) = st;
        }
}

extern "C" void kernel_launch(void* const* d_in, const int* in_sizes, int n_in,
                              void* d_out, int out_size, void* d_ws, size_t ws_size,
                              hipStream_t stream) {
    const float* x     = (const float*)d_in[0];
    const float* w_qkv = (const float*)d_in[1];
    const float* w_out = (const float*)d_in[2];
    const float* b_out = (const float*)d_in[3];
    float* out = (float*)d_out;

    char* ws = (char*)d_ws;
    f16* qh    = (f16*)(ws);                        // 4 MB
    f16* kh    = (f16*)(ws + (4u << 20));           // 4 MB
    f16* vh    = (f16*)(ws + (8u << 20));           // 4 MB
    f16* att16 = (f16*)(ws + (12u << 20));          // 4 MB

    qkv_mega<<<dim3(NN / 32, 1, BB), 256, 0, stream>>>(x, w_qkv, qh, kh, vh);

    if (ws_size >= (50ull << 20)) {
        // SPLIT=4: op 32 MB @16, lp 1 MB @48
        float* op = (float*)(ws + (16ull << 20));
        float* lp = (float*)(ws + (48ull << 20));
        attn_mfma<4><<<dim3(1024), 256, 0, stream>>>(qh, kh, vh, op, lp, att16);
        attn_combine<<<dim3(2048), 256, 0, stream>>>(op, lp, att16, 4);
    } else if (ws_size >= (33ull << 20)) {
        // SPLIT=2: op 16 MB @16, lp 0.5 MB @32
        float* op = (float*)(ws + (16ull << 20));
        float* lp = (float*)(ws + (32ull << 20));
        attn_mfma<2><<<dim3(512), 256, 0, stream>>>(qh, kh, vh, op, lp, att16);
        attn_combine<<<dim3(2048), 256, 0, stream>>>(op, lp, att16, 2);
    } else {
        attn_mfma<1><<<dim3(256), 256, 0, stream>>>(qh, kh, vh, nullptr, nullptr, att16);
    }

    out_mfma<<<dim3(NN / 128, CC / 64, BB), 256, 0, stream>>>(att16, w_out, b_out, out);
}

// Round 8
// 151.198 us; speedup vs baseline: 1.0477x; 1.0153x over previous
//
#include <hip/hip_runtime.h>
#include <math.h>

#define BB 4
#define CC 256
#define NHEAD 4
#define DH 32
#define NN 4096
#define HID 128

typedef _Float16 f16;
typedef _Float16 f16x8 __attribute__((ext_vector_type(8)));
typedef _Float16 f16x4 __attribute__((ext_vector_type(4)));
typedef float f32x4 __attribute__((ext_vector_type(4)));
typedef unsigned int u32x4 __attribute__((ext_vector_type(4)));

#define QPRESCALE 14.42695041f
#define NSHIFT 14.42695041f

#if __has_builtin(__builtin_amdgcn_exp2f)
#define EXP2F(x) __builtin_amdgcn_exp2f(x)
#else
#define EXP2F(x) __expf((x)*0.6931471805599453f)
#endif

__device__ __forceinline__ f16x8 cvt8(const float* p) {
    float4 a = *(const float4*)p;
    float4 b = *(const float4*)(p + 4);
    f16x8 r;
    r[0] = (f16)a.x; r[1] = (f16)a.y; r[2] = (f16)a.z; r[3] = (f16)a.w;
    r[4] = (f16)b.x; r[5] = (f16)b.y; r[6] = (f16)b.z; r[7] = (f16)b.w;
    return r;
}

// ---------------- kernel 1: qkv GEMM, in-LDS x transpose + l2norm ----------
// R5 analysis: 2 blocks/CU + 6-frag cvt8 chains per k-step = latency-bound.
// Now: block = 32 i x 128 o (blockIdx.y picks Q/K/V o-range -> branch is
// block-uniform, each wave owns exactly ONE head of 32 o), grid 1536 =
// 6 blocks/CU by natural VGPR occupancy (~40 regs; launch_bounds kept at the
// standard (256,4) -- R7: the (256,6) variant was the only untested compiler
// input in the twice-failed build). x re-read 3x (50 MB, L3-resident).
#define XROW 40   // 32 c + 8 pad

__global__ __launch_bounds__(256, 4) void qkv_mega(const float* __restrict__ x,
                                                   const float* __restrict__ wq,
                                                   f16* __restrict__ qh,
                                                   f16* __restrict__ kh,
                                                   f16* __restrict__ vh) {
    __shared__ __align__(16) f16 xl[32 * XROW];
    int t = threadIdx.x;
    int wave = t >> 6, lane = t & 63;
    int quad = lane >> 4, col = lane & 15;
    int b = blockIdx.z;
    int i0 = blockIdx.x * 32;
    int o0w = blockIdx.y * 128 + wave * 32;   // one 32-dh head per wave

    int sc = t >> 3;      // 0..31: local c row
    int iseg = t & 7;     // i group of 4
    const float* xb = x + (size_t)b * CC * NN + i0 + iseg * 4;

    f32x4 c[2][2];
#pragma unroll
    for (int mt = 0; mt < 2; mt++)
#pragma unroll
        for (int nt = 0; nt < 2; nt++) c[mt][nt] = f32x4{0.f, 0.f, 0.f, 0.f};

#pragma unroll
    for (int k0 = 0; k0 < CC; k0 += 32) {
        float4 xv = *(const float4*)(xb + (size_t)(k0 + sc) * NN);
        __syncthreads();   // prior iter's frag reads done before overwrite
        xl[(iseg * 4 + 0) * XROW + sc] = (f16)xv.x;
        xl[(iseg * 4 + 1) * XROW + sc] = (f16)xv.y;
        xl[(iseg * 4 + 2) * XROW + sc] = (f16)xv.z;
        xl[(iseg * 4 + 3) * XROW + sc] = (f16)xv.w;
        __syncthreads();
        f16x8 bf0 = *(const f16x8*)(xl + (size_t)col * XROW + quad * 8);
        f16x8 bf1 = *(const f16x8*)(xl + (size_t)(16 + col) * XROW + quad * 8);
#pragma unroll
        for (int mt = 0; mt < 2; mt++) {
            f16x8 a = cvt8(wq + (size_t)(o0w + mt * 16 + col) * CC + k0 + quad * 8);
            c[mt][0] = __builtin_amdgcn_mfma_f32_16x16x32_f16(a, bf0, c[mt][0], 0, 0, 0);
            c[mt][1] = __builtin_amdgcn_mfma_f32_16x16x32_f16(a, bf1, c[mt][1], 0, 0, 0);
        }
    }

    if (blockIdx.y < 2) {                 // Q (y=0) or K (y=1): l2norm
        int isQ = (blockIdx.y == 0);
        f16* dst = isQ ? qh : kh;
        int h = wave;                      // head index within b
        float pre = isQ ? QPRESCALE : 1.0f;
#pragma unroll
        for (int nt = 0; nt < 2; nt++) {
            float ss = 0.f;
#pragma unroll
            for (int m2 = 0; m2 < 2; m2++)
#pragma unroll
                for (int r = 0; r < 4; r++) {
                    float v = c[m2][nt][r];
                    ss = fmaf(v, v, ss);
                }
            ss += __shfl_xor(ss, 16);
            ss += __shfl_xor(ss, 32);
            float inv = pre / fmaxf(sqrtf(ss), 1e-12f);
            size_t row = ((size_t)(b * 4 + h) * NN + i0 + nt * 16 + col) * 32;
#pragma unroll
            for (int m2 = 0; m2 < 2; m2++) {
                f16x4 st;
#pragma unroll
                for (int r = 0; r < 4; r++) st[r] = (f16)(c[m2][nt][r] * inv);
                *(f16x4*)(dst + row + m2 * 16 + quad * 4) = st;
            }
        }
    } else {                               // V: [bh][d][i] layout
        int h = wave;
#pragma unroll
        for (int nt = 0; nt < 2; nt++) {
            int i = i0 + nt * 16 + col;
#pragma unroll
            for (int m2 = 0; m2 < 2; m2++)
#pragma unroll
                for (int r = 0; r < 4; r++)
                    vh[((size_t)(b * 4 + h) * 32 + m2 * 16 + quad * 4 + r) * NN + i] =
                        (f16)c[m2][nt][r];
        }
    }
}

// ---------------- kernel 2: LDS-staged MFMA flash attention, key-split ------
#define KROW 40   // 32 d + 8 pad (f16) -> 80 B rows, b128-clean
#define VROW 72   // 64 keys + 8 pad   -> 144 B rows, b128-clean

__device__ __forceinline__ f16x8 expblk2(f32x4 sa, f32x4 sb) {
    u32x4 w;
    w[0] = __builtin_bit_cast(unsigned int,
            __builtin_amdgcn_cvt_pkrtz(EXP2F(sa[0]), EXP2F(sa[1])));
    w[1] = __builtin_bit_cast(unsigned int,
            __builtin_amdgcn_cvt_pkrtz(EXP2F(sa[2]), EXP2F(sa[3])));
    w[2] = __builtin_bit_cast(unsigned int,
            __builtin_amdgcn_cvt_pkrtz(EXP2F(sb[0]), EXP2F(sb[1])));
    w[3] = __builtin_bit_cast(unsigned int,
            __builtin_amdgcn_cvt_pkrtz(EXP2F(sb[2]), EXP2F(sb[3])));
    return __builtin_bit_cast(f16x8, w);
}

// one 32-key group (jb = 0 or 32) x 64 q (4 q-frags)
__device__ __forceinline__ void compute_g(const f16* kl, const f16* vl, int jb,
                                          int col, int quad, const f16x8 (&qB)[4],
                                          f32x4 (&o)[4][2], f32x4 (&lf)[4]) {
    f16x8 kA = *(const f16x8*)(kl + (jb + col) * KROW + quad * 8);
    f16x8 kB = *(const f16x8*)(kl + (jb + 16 + col) * KROW + quad * 8);
    f16x8 v0 = *(const f16x8*)(vl + col * VROW + jb + quad * 8);
    f16x8 v1 = *(const f16x8*)(vl + (16 + col) * VROW + jb + quad * 8);
    const f32x4 zs = {-NSHIFT, -NSHIFT, -NSHIFT, -NSHIFT};
    f16 one = (f16)1.0f;
    f16x8 ones = {one, one, one, one, one, one, one, one};
#pragma unroll
    for (int f = 0; f < 4; f++) {
        f32x4 sa = __builtin_amdgcn_mfma_f32_16x16x32_f16(kA, qB[f], zs, 0, 0, 0);
        f32x4 sb = __builtin_amdgcn_mfma_f32_16x16x32_f16(kB, qB[f], zs, 0, 0, 0);
        f16x8 p = expblk2(sa, sb);
        o[f][0] = __builtin_amdgcn_mfma_f32_16x16x32_f16(p, v0, o[f][0], 0, 0, 0);
        o[f][1] = __builtin_amdgcn_mfma_f32_16x16x32_f16(p, v1, o[f][1], 0, 0, 0);
        lf[f]   = __builtin_amdgcn_mfma_f32_16x16x32_f16(p, ones, lf[f], 0, 0, 0);
    }
}

template <int SPLIT>
__global__ __launch_bounds__(256, 4) void attn_mfma(const f16* __restrict__ qh,
                                                    const f16* __restrict__ kh,
                                                    const f16* __restrict__ vh,
                                                    float* __restrict__ op,
                                                    float* __restrict__ lp,
                                                    f16* __restrict__ att16) {
    __shared__ __align__(16) f16 klds[2][64 * KROW];
    __shared__ __align__(16) f16 vlds[2][32 * VROW];
    int t = threadIdx.x;
    int wave = t >> 6, lane = t & 63;
    int quad = lane >> 4, col = lane & 15;

    // grid = 256*SPLIT blocks; xcd grouping keeps K/V L2-resident (2 bh/XCD).
    int bid = blockIdx.x;
    int xcd = bid & 7;
    int slot = bid >> 3;                      // 0 .. 32*SPLIT-1
    int bh = xcd * 2 + slot / (16 * SPLIT);   // 0..15
    int rem = slot % (16 * SPLIT);
    int s = rem >> 4;                         // 0..SPLIT-1
    int i0 = (rem & 15) * 256;
    int iw = i0 + wave * 64;

    const int NT = 64 / SPLIT;                // 64-key tiles per block
    int kbase = s * (NN / SPLIT);

    const f16* qb = qh + (size_t)bh * NN * 32;
    const f16* kb = kh + (size_t)bh * NN * 32 + (size_t)kbase * 32;
    const f16* vb = vh + (size_t)bh * 32 * NN + kbase;

    f16x8 qB[4];
#pragma unroll
    for (int f = 0; f < 4; f++)
        qB[f] = *(const f16x8*)(qb + (size_t)(iw + f * 16 + col) * 32 + quad * 8);

    f32x4 o[4][2], lf[4];
#pragma unroll
    for (int f = 0; f < 4; f++) {
        o[f][0] = f32x4{0.f, 0.f, 0.f, 0.f};
        o[f][1] = f32x4{0.f, 0.f, 0.f, 0.f};
        lf[f]   = f32x4{0.f, 0.f, 0.f, 0.f};
    }

    // staging: K rows gathered in PV-permuted order (ksrc bijection) so P
    // frag concat is the native 16x16x32 A layout; V natural [dh][key].
    int ktr = t >> 2, kts = t & 3;
    int ksrc = (ktr & 32) | ((ktr & 12) << 1) | ((ktr & 16) >> 2) | (ktr & 3);
    int vtr = t >> 3, vts = t & 7;

    f16x8 kr, vr;
    kr = *(const f16x8*)(kb + (size_t)(0 + ksrc) * 32 + kts * 8);
    vr = *(const f16x8*)(vb + (size_t)vtr * NN + 0 + vts * 8);
    *(f16x8*)(&klds[0][0] + ktr * KROW + kts * 8) = kr;
    *(f16x8*)(&vlds[0][0] + vtr * VROW + vts * 8) = vr;
    __syncthreads();
    kr = *(const f16x8*)(kb + (size_t)(64 + ksrc) * 32 + kts * 8);
    vr = *(const f16x8*)(vb + (size_t)vtr * NN + 64 + vts * 8);

    for (int tile = 0; tile < NT - 2; tile++) {
        int buf = tile & 1;
        const f16* kl = &klds[buf][0];
        const f16* vl = &vlds[buf][0];
        compute_g(kl, vl, 0, col, quad, qB, o, lf);
        compute_g(kl, vl, 32, col, quad, qB, o, lf);
        *(f16x8*)(&klds[buf ^ 1][0] + ktr * KROW + kts * 8) = kr;
        *(f16x8*)(&vlds[buf ^ 1][0] + vtr * VROW + vts * 8) = vr;
        __syncthreads();
        int j0 = (tile + 2) * 64;
        kr = *(const f16x8*)(kb + (size_t)(j0 + ksrc) * 32 + kts * 8);
        vr = *(const f16x8*)(vb + (size_t)vtr * NN + j0 + vts * 8);
    }
    {   // tile NT-2 (buf 0); kr/vr hold tile NT-1
        compute_g(&klds[0][0], &vlds[0][0], 0, col, quad, qB, o, lf);
        compute_g(&klds[0][0], &vlds[0][0], 32, col, quad, qB, o, lf);
        *(f16x8*)(&klds[1][0] + ktr * KROW + kts * 8) = kr;
        *(f16x8*)(&vlds[1][0] + vtr * VROW + vts * 8) = vr;
        __syncthreads();
    }
    {   // tile NT-1 (buf 1)
        compute_g(&klds[1][0], &vlds[1][0], 0, col, quad, qB, o, lf);
        compute_g(&klds[1][0], &vlds[1][0], 32, col, quad, qB, o, lf);
    }

    // lf[f][r] = sum_k p for query row iw + f*16 + quad*4 + r (replicated
    // across col lanes).
    if constexpr (SPLIT == 1) {
        int b = bh >> 2, h = bh & 3;
        f16* ab = att16 + (size_t)b * NN * HID + h * 32;
#pragma unroll
        for (int f = 0; f < 4; f++)
#pragma unroll
            for (int r = 0; r < 4; r++) {
                float inv = __builtin_amdgcn_rcpf(lf[f][r]);
                size_t row = (size_t)(iw + f * 16 + quad * 4 + r) * HID;
                ab[row + col]      = (f16)(o[f][0][r] * inv);
                ab[row + 16 + col] = (f16)(o[f][1][r] * inv);
            }
    } else {
        // f32 partials: op[(s*16+bh)][q][dh], lp[(s*16+bh)][q]
        float* ob = op + (size_t)(s * 16 + bh) * NN * 32;
#pragma unroll
        for (int f = 0; f < 4; f++)
#pragma unroll
            for (int r = 0; r < 4; r++) {
                size_t rr = (size_t)(iw + f * 16 + quad * 4 + r) * 32;
                ob[rr + col]      = o[f][0][r];
                ob[rr + 16 + col] = o[f][1][r];
            }
        if (col == 0) {
            float* lb = lp + (size_t)(s * 16 + bh) * NN;
#pragma unroll
            for (int f = 0; f < 4; f++)
#pragma unroll
                for (int r = 0; r < 4; r++)
                    lb[iw + f * 16 + quad * 4 + r] = lf[f][r];
        }
    }
}

// ---------------- kernel 2b: combine split partials -> att16 ----------------
__global__ __launch_bounds__(256) void attn_combine(const float* __restrict__ op,
                                                    const float* __restrict__ lp,
                                                    f16* __restrict__ att16,
                                                    int nsplit) {
    int gid = blockIdx.x * 256 + threadIdx.x;   // 16*4096 rows * 8 segs
    int rowid = gid >> 3;
    int seg = gid & 7;
    int bh = rowid >> 12;
    int q = rowid & 4095;

    float l = 0.f;
    f32x4 acc = {0.f, 0.f, 0.f, 0.f};
    for (int s = 0; s < nsplit; s++) {
        l += lp[(size_t)(s * 16 + bh) * NN + q];
        f32x4 a = *(const f32x4*)(op + ((size_t)(s * 16 + bh) * NN + q) * 32 + seg * 4);
        acc += a;
    }
    float inv = __builtin_amdgcn_rcpf(l);
    int b = bh >> 2, h = bh & 3;
    f16x4 st;
    st[0] = (f16)(acc[0] * inv);
    st[1] = (f16)(acc[1] * inv);
    st[2] = (f16)(acc[2] * inv);
    st[3] = (f16)(acc[3] * inv);
    *(f16x4*)(att16 + ((size_t)b * NN + q) * HID + h * 32 + seg * 4) = st;
}

// ---------------- kernel 3: output projection (MFMA) + bias ----------------
// R5 analysis: per-k-step 8xfloat4 + 16 cvt per thread at 2 blocks/CU =
// latency-bound. Now: wo tile staged ONCE per block to LDS as f16 (shared by
// all 4 waves), block = 64 i x 64 o, grid 1024 = 4 blocks/CU; inner loop is
// 1 global b128 + 4 LDS b128 + 4 MFMA per k-step.
#define WROW 136   // 128 k + 8 pad (f16) -> 272 B rows, quarter-wave 2-way

__global__ __launch_bounds__(256, 4) void out_mfma(const f16* __restrict__ att16,
                                                   const float* __restrict__ wo,
                                                   const float* __restrict__ bo,
                                                   float* __restrict__ out) {
    __shared__ __align__(16) f16 wol[64 * WROW];
    int t = threadIdx.x;
    int wave = t >> 6, lane = t & 63;
    int quad = lane >> 4, col = lane & 15;
    int b = blockIdx.z;
    int i0w = blockIdx.x * 64 + wave * 16;
    int o0 = blockIdx.y * 64;
    const f16* ab = att16 + (size_t)b * NN * HID;

    // stage wo[o0..o0+64)[0..128) -> f16 LDS (each thread: 1 row-quarter)
    {
        int row = t >> 2;            // 0..63
        int kq = (t & 3) * 32;       // 0,32,64,96
        const float* src = wo + (size_t)(o0 + row) * HID + kq;
        f16* d = wol + row * WROW + kq;
#pragma unroll
        for (int j = 0; j < 4; j++) {
            float4 a = *(const float4*)(src + j * 8);
            float4 bq = *(const float4*)(src + j * 8 + 4);
            f16x8 s;
            s[0] = (f16)a.x; s[1] = (f16)a.y; s[2] = (f16)a.z; s[3] = (f16)a.w;
            s[4] = (f16)bq.x; s[5] = (f16)bq.y; s[6] = (f16)bq.z; s[7] = (f16)bq.w;
            *(f16x8*)(d + j * 8) = s;
        }
    }
    __syncthreads();

    const f32x4 z = {0.f, 0.f, 0.f, 0.f};
    f32x4 c[4];
#pragma unroll
    for (int ot = 0; ot < 4; ot++) c[ot] = z;

#pragma unroll
    for (int k0 = 0; k0 < HID; k0 += 32) {
        f16x8 a0 = *(const f16x8*)(ab + (size_t)(i0w + col) * HID + k0 + quad * 8);
#pragma unroll
        for (int ot = 0; ot < 4; ot++) {
            f16x8 bf = *(const f16x8*)(wol + (size_t)(ot * 16 + col) * WROW + k0 + quad * 8);
            c[ot] = __builtin_amdgcn_mfma_f32_16x16x32_f16(a0, bf, c[ot], 0, 0, 0);
        }
    }

#pragma unroll
    for (int ot = 0; ot < 4; ot++) {
        int o = o0 + ot * 16 + col;
        float bias = bo[o];
        int i = i0w + quad * 4;
        float4 st = {c[ot][0] + bias, c[ot][1] + bias,
                     c[ot][2] + bias, c[ot][3] + bias};
        *(float4*)(out + ((size_t)b * CC + o) * NN + i) = st;
    }
}

extern "C" void kernel_launch(void* const* d_in, const int* in_sizes, int n_in,
                              void* d_out, int out_size, void* d_ws, size_t ws_size,
                              hipStream_t stream) {
    const float* x     = (const float*)d_in[0];
    const float* w_qkv = (const float*)d_in[1];
    const float* w_out = (const float*)d_in[2];
    const float* b_out = (const float*)d_in[3];
    float* out = (float*)d_out;

    char* ws = (char*)d_ws;
    f16* qh    = (f16*)(ws);                        // 4 MB
    f16* kh    = (f16*)(ws + (4u << 20));           // 4 MB
    f16* vh    = (f16*)(ws + (8u << 20));           // 4 MB
    f16* att16 = (f16*)(ws + (12u << 20));          // 4 MB

    qkv_mega<<<dim3(NN / 32, 3, BB), 256, 0, stream>>>(x, w_qkv, qh, kh, vh);

    if (ws_size >= (50ull << 20)) {
        // SPLIT=4: op 32 MB @16, lp 1 MB @48
        float* op = (float*)(ws + (16ull << 20));
        float* lp = (float*)(ws + (48ull << 20));
        attn_mfma<4><<<dim3(1024), 256, 0, stream>>>(qh, kh, vh, op, lp, att16);
        attn_combine<<<dim3(2048), 256, 0, stream>>>(op, lp, att16, 4);
    } else if (ws_size >= (33ull << 20)) {
        // SPLIT=2: op 16 MB @16, lp 0.5 MB @32
        float* op = (float*)(ws + (16ull << 20));
        float* lp = (float*)(ws + (32ull << 20));
        attn_mfma<2><<<dim3(512), 256, 0, stream>>>(qh, kh, vh, op, lp, att16);
        attn_combine<<<dim3(2048), 256, 0, stream>>>(op, lp, att16, 2);
    } else {
        attn_mfma<1><<<dim3(256), 256, 0, stream>>>(qh, kh, vh, nullptr, nullptr, att16);
    }

    out_mfma<<<dim3(NN / 64, CC / 64, BB), 256, 0, stream>>>(att16, w_out, b_out, out);
}